// Round 2
// baseline (107.178 us; speedup 1.0000x reference)
//
#include <hip/hip_runtime.h>
#include <hip/hip_bf16.h>

#define N_PAIR 4096
#define N_ROW  8192
#define DIM    128
#define LDA    136   // padded LDS stride in bf16 elems (272B, 16B-aligned)

typedef __attribute__((ext_vector_type(8))) short   short8;
typedef __attribute__((ext_vector_type(4))) float   f32x4;
typedef __bf16 bf16x8 __attribute__((ext_vector_type(8)));

__device__ inline unsigned short f2bf(float x) {
    union { float f; unsigned int u; } c; c.f = x;
    unsigned int u = c.u;
    unsigned int r = (u + 0x7fffu + ((u >> 16) & 1u)) >> 16;
    return (unsigned short)r;
}

// K1: interleave + L2-normalize rows -> zh (bf16 [8192][128]), invn (fp32 [8192])
__global__ __launch_bounds__(256) void k_normalize(const float* __restrict__ zi,
                                                   const float* __restrict__ zj,
                                                   unsigned short* __restrict__ zh,
                                                   float* __restrict__ invn) {
    const int wid  = threadIdx.x >> 6;
    const int lane = threadIdx.x & 63;
    const int row  = blockIdx.x * 4 + wid;          // 0..8191
    const float* src = (row & 1) ? zj : zi;
    const int srow = row >> 1;
    float2 v = *(const float2*)&src[srow * DIM + lane * 2];
    float ss = v.x * v.x + v.y * v.y;
#pragma unroll
    for (int off = 1; off < 64; off <<= 1) ss += __shfl_xor(ss, off);
    const float inv = rsqrtf(ss);
    unsigned int u0 = f2bf(v.x * inv);
    unsigned int u1 = f2bf(v.y * inv);
    ((unsigned int*)zh)[row * (DIM / 2) + lane] = (u1 << 16) | u0;
    if (lane == 0) invn[row] = inv;
}

// K2: fused S = Zh*Zh^T tile -> exp2(2*log2e*s) -> row-sum (diag excluded) -> atomic
__global__ __launch_bounds__(256) void k_simsum(const unsigned short* __restrict__ zh,
                                                float* __restrict__ rowsum) {
    __shared__ unsigned short As[128 * LDA];
    __shared__ unsigned short Bs[128 * LDA];
    const int tid  = threadIdx.x;
    const int lane = tid & 63;
    const int wid  = tid >> 6;
    const int wr   = wid >> 1, wc = wid & 1;
    const int arow0 = blockIdx.y * 128;
    const int bcol0 = blockIdx.x * 128;

#pragma unroll
    for (int it = 0; it < 8; ++it) {
        int c   = it * 256 + tid;        // chunk 0..2047 (16 chunks/row)
        int r   = c >> 4;
        int col = (c & 15) * 8;
        *(short8*)&As[r * LDA + col] = *(const short8*)&zh[(arow0 + r) * DIM + col];
        *(short8*)&Bs[r * LDA + col] = *(const short8*)&zh[(bcol0 + r) * DIM + col];
    }
    __syncthreads();

    const int l15 = lane & 15, lhi = lane >> 4;
    f32x4 acc[4][4] = {};
#pragma unroll
    for (int kk = 0; kk < 4; ++kk) {
        bf16x8 a[4], b[4];
#pragma unroll
        for (int m = 0; m < 4; ++m)
            a[m] = *(const bf16x8*)&As[(wr * 64 + m * 16 + l15) * LDA + kk * 32 + lhi * 8];
#pragma unroll
        for (int n = 0; n < 4; ++n)
            b[n] = *(const bf16x8*)&Bs[(wc * 64 + n * 16 + l15) * LDA + kk * 32 + lhi * 8];
#pragma unroll
        for (int m = 0; m < 4; ++m)
#pragma unroll
            for (int n = 0; n < 4; ++n)
                acc[m][n] = __builtin_amdgcn_mfma_f32_16x16x32_bf16(a[m], b[n], acc[m][n], 0, 0, 0);
    }

    const float K2E = 2.8853900817779268f;  // 2/ln(2): exp(2s) = exp2(K2E*s)
#pragma unroll
    for (int m = 0; m < 4; ++m) {
        const int grow_base = arow0 + wr * 64 + m * 16 + lhi * 4;
#pragma unroll
        for (int j = 0; j < 4; ++j) {
            const int grow = grow_base + j;
            float partial = 0.f;
#pragma unroll
            for (int n = 0; n < 4; ++n) {
                const int gcol = bcol0 + wc * 64 + n * 16 + l15;
                float v = exp2f(K2E * acc[m][n][j]);
                partial += (gcol == grow) ? 0.f : v;   // exclude diagonal
            }
#pragma unroll
            for (int off = 1; off < 16; off <<= 1)
                partial += __shfl_xor(partial, off);
            if (l15 == 0) atomicAdd(&rowsum[grow], partial);
        }
    }
}

// K3: fp32 partner similarity pd[k] = dot(z_i[k], z_j[k]) * invn[2k] * invn[2k+1]
__global__ __launch_bounds__(256) void k_partner(const float* __restrict__ zi,
                                                 const float* __restrict__ zj,
                                                 const float* __restrict__ invn,
                                                 float* __restrict__ pd) {
    const int wid  = threadIdx.x >> 6;
    const int lane = threadIdx.x & 63;
    const int k    = blockIdx.x * 4 + wid;          // 0..4095
    float2 a = *(const float2*)&zi[k * DIM + lane * 2];
    float2 b = *(const float2*)&zj[k * DIM + lane * 2];
    float d = a.x * b.x + a.y * b.y;
#pragma unroll
    for (int off = 1; off < 64; off <<= 1) d += __shfl_xor(d, off);
    if (lane == 0) pd[k] = d * invn[2 * k] * invn[2 * k + 1];
}

// K4: loss = mean_i( ln(rowsum[i]) - 2*pd[i>>1] ), double accumulation
__global__ __launch_bounds__(256) void k_loss(const float* __restrict__ rowsum,
                                              const float* __restrict__ pd,
                                              float* __restrict__ out) {
    __shared__ double red[256];
    const float LN2 = 0.6931471805599453f;
    double local = 0.0;
    for (int i = threadIdx.x; i < N_ROW; i += 256)
        local += (double)(log2f(rowsum[i]) * LN2 - 2.f * pd[i >> 1]);
    red[threadIdx.x] = local;
    __syncthreads();
    for (int s = 128; s > 0; s >>= 1) {
        if (threadIdx.x < s) red[threadIdx.x] += red[threadIdx.x + s];
        __syncthreads();
    }
    if (threadIdx.x == 0) out[0] = (float)(red[0] / (double)N_ROW);
}

extern "C" void kernel_launch(void* const* d_in, const int* in_sizes, int n_in,
                              void* d_out, int out_size, void* d_ws, size_t ws_size,
                              hipStream_t stream) {
    const float* zi = (const float*)d_in[0];
    const float* zj = (const float*)d_in[1];
    char* ws = (char*)d_ws;
    unsigned short* zh = (unsigned short*)ws;                       // 2 MiB
    float* invn   = (float*)(ws + 2 * 1024 * 1024);                 // 32 KiB
    float* rowsum = (float*)(ws + 2 * 1024 * 1024 + 32 * 1024);     // 32 KiB
    float* pd     = (float*)(ws + 2 * 1024 * 1024 + 64 * 1024);     // 16 KiB

    hipMemsetAsync(rowsum, 0, N_ROW * sizeof(float), stream);
    k_normalize<<<N_ROW / 4, 256, 0, stream>>>(zi, zj, zh, invn);
    dim3 grid(64, 64);
    k_simsum<<<grid, 256, 0, stream>>>(zh, rowsum);
    k_partner<<<N_PAIR / 4, 256, 0, stream>>>(zi, zj, invn, pd);
    k_loss<<<1, 256, 0, stream>>>(rowsum, pd, (float*)d_out);
}

// Round 3
// 60.851 us; speedup vs baseline: 1.7613x; 1.7613x over previous
//
#include <hip/hip_runtime.h>
#include <hip/hip_bf16.h>

#define N_PAIR 4096
#define N_ROW  8192
#define DIM    128
#define NTILE  64            // 8192 / 128 tile blocks per dim
#define NBLK   (NTILE * (NTILE + 1) / 2)   // 2080 upper-tri tile blocks

typedef __attribute__((ext_vector_type(4))) float   f32x4;
typedef __bf16 bf16x8 __attribute__((ext_vector_type(8)));

__device__ inline unsigned short f2bf(float x) {
    union { float f; unsigned int u; } c; c.f = x;
    unsigned int u = c.u;
    return (unsigned short)((u + 0x7fffu + ((u >> 16) & 1u)) >> 16);
}

// K1: fused interleave + L2-normalize -> zh (bf16 [8192][128]); partner dot -> pd;
//     zero rowsum. One pair (rows 2k, 2k+1) per wave.
__global__ __launch_bounds__(256) void k_prep(const float* __restrict__ zi,
                                              const float* __restrict__ zj,
                                              unsigned short* __restrict__ zh,
                                              float* __restrict__ pd,
                                              float* __restrict__ rowsum) {
    const int wid  = threadIdx.x >> 6;
    const int lane = threadIdx.x & 63;
    const int k    = blockIdx.x * 4 + wid;          // pair 0..4095
    float2 a = *(const float2*)&zi[k * DIM + lane * 2];
    float2 b = *(const float2*)&zj[k * DIM + lane * 2];
    float ssi = a.x * a.x + a.y * a.y;
    float ssj = b.x * b.x + b.y * b.y;
    float dot = a.x * b.x + a.y * b.y;
#pragma unroll
    for (int off = 1; off < 64; off <<= 1) {
        ssi += __shfl_xor(ssi, off);
        ssj += __shfl_xor(ssj, off);
        dot += __shfl_xor(dot, off);
    }
    const float invi = rsqrtf(ssi), invj = rsqrtf(ssj);
    unsigned int wi = ((unsigned int)f2bf(a.y * invi) << 16) | f2bf(a.x * invi);
    unsigned int wj = ((unsigned int)f2bf(b.y * invj) << 16) | f2bf(b.x * invj);
    ((unsigned int*)zh)[(2 * k)     * (DIM / 2) + lane] = wi;
    ((unsigned int*)zh)[(2 * k + 1) * (DIM / 2) + lane] = wj;
    if (lane == 0) {
        pd[k] = dot * invi * invj;
        rowsum[2 * k]     = 0.f;
        rowsum[2 * k + 1] = 0.f;
    }
}

// K2: upper-tri tiles of S = Zh*Zh^T, no LDS (zh is L2-resident), fused
//     exp2 epilogue; off-diag tiles feed row- AND col-sums.
__global__ __launch_bounds__(256) void k_simsum(const unsigned short* __restrict__ zh,
                                                float* __restrict__ rowsum) {
    // map linear block -> (bx, by) with by <= bx
    const int t = blockIdx.x;
    int bx = (int)((sqrtf(8.f * (float)t + 1.f) - 1.f) * 0.5f);
    while ((bx + 1) * (bx + 2) / 2 <= t) ++bx;
    while (bx * (bx + 1) / 2 > t) --bx;
    const int by = t - bx * (bx + 1) / 2;
    const bool diag = (bx == by);

    const int tid  = threadIdx.x;
    const int lane = tid & 63;
    const int wid  = tid >> 6;
    const int wr   = wid >> 1, wc = wid & 1;
    const int l15  = lane & 15, lhi = lane >> 4;
    const int arow0 = by * 128;
    const int bcol0 = bx * 128;

    f32x4 acc[4][4] = {};
#pragma unroll
    for (int kk = 0; kk < 4; ++kk) {
        bf16x8 a[4], b[4];
#pragma unroll
        for (int m = 0; m < 4; ++m)
            a[m] = *(const bf16x8*)&zh[(arow0 + wr * 64 + m * 16 + l15) * DIM + kk * 32 + lhi * 8];
#pragma unroll
        for (int n = 0; n < 4; ++n)
            b[n] = *(const bf16x8*)&zh[(bcol0 + wc * 64 + n * 16 + l15) * DIM + kk * 32 + lhi * 8];
#pragma unroll
        for (int m = 0; m < 4; ++m)
#pragma unroll
            for (int n = 0; n < 4; ++n)
                acc[m][n] = __builtin_amdgcn_mfma_f32_16x16x32_bf16(a[m], b[n], acc[m][n], 0, 0, 0);
    }

    const float K2E = 2.8853900817779268f;  // 2/ln(2): exp(2s) = exp2(K2E*s)
    float csum[4] = {0.f, 0.f, 0.f, 0.f};
#pragma unroll
    for (int m = 0; m < 4; ++m) {
        const int grow_base = arow0 + wr * 64 + m * 16 + lhi * 4;
#pragma unroll
        for (int j = 0; j < 4; ++j) {
            const int grow = grow_base + j;
            float rpart = 0.f;
#pragma unroll
            for (int n = 0; n < 4; ++n) {
                float v = exp2f(K2E * acc[m][n][j]);
                if (diag) {
                    const int gcol = bcol0 + wc * 64 + n * 16 + l15;
                    v = (gcol == grow) ? 0.f : v;
                }
                rpart += v;
                csum[n] += v;
            }
#pragma unroll
            for (int off = 1; off < 16; off <<= 1)
                rpart += __shfl_xor(rpart, off);
            if (l15 == 0) atomicAdd(&rowsum[grow], rpart);
        }
    }
    if (!diag) {
#pragma unroll
        for (int n = 0; n < 4; ++n) {
            float c = csum[n];
            c += __shfl_xor(c, 16);
            c += __shfl_xor(c, 32);
            if (lane < 16) atomicAdd(&rowsum[bcol0 + wc * 64 + n * 16 + l15], c);
        }
    }
}

// K3: loss = mean_i( ln(rowsum[i]) - 2*pd[i>>1] ), double accumulation
__global__ __launch_bounds__(1024) void k_loss(const float* __restrict__ rowsum,
                                               const float* __restrict__ pd,
                                               float* __restrict__ out) {
    __shared__ double red[1024];
    const float LN2 = 0.6931471805599453f;
    double local = 0.0;
    for (int i = threadIdx.x; i < N_ROW; i += 1024)
        local += (double)(log2f(rowsum[i]) * LN2 - 2.f * pd[i >> 1]);
    red[threadIdx.x] = local;
    __syncthreads();
    for (int s = 512; s > 0; s >>= 1) {
        if (threadIdx.x < s) red[threadIdx.x] += red[threadIdx.x + s];
        __syncthreads();
    }
    if (threadIdx.x == 0) out[0] = (float)(red[0] / (double)N_ROW);
}

extern "C" void kernel_launch(void* const* d_in, const int* in_sizes, int n_in,
                              void* d_out, int out_size, void* d_ws, size_t ws_size,
                              hipStream_t stream) {
    const float* zi = (const float*)d_in[0];
    const float* zj = (const float*)d_in[1];
    char* ws = (char*)d_ws;
    unsigned short* zh = (unsigned short*)ws;                     // 2 MiB
    float* rowsum = (float*)(ws + 2 * 1024 * 1024);               // 32 KiB
    float* pd     = (float*)(ws + 2 * 1024 * 1024 + 32 * 1024);   // 16 KiB

    k_prep<<<N_PAIR / 4, 256, 0, stream>>>(zi, zj, zh, pd, rowsum);
    k_simsum<<<NBLK, 256, 0, stream>>>(zh, rowsum);
    k_loss<<<1, 1024, 0, stream>>>(rowsum, pd, (float*)d_out);
}